// Round 18
// baseline (734.296 us; speedup 1.0000x reference)
//
#include <hip/hip_runtime.h>
#include <hip/hip_bf16.h>

// ConvNetLayer fused pipeline, MI355X (gfx950). Round 18.
//
// R18 = R17 + 2-deep gather pipeline in bond_gemm: tile loop unrolled into
// A/B halves with two gather register sets; ex/ey gathers for tile t+2s are
// issued at half-t's (c) and consumed one full unrolled iteration later
// (~2-3x latency cover vs 1 phase-set). Xb stream stays 1-deep (sequential).
// g2 rows prefetched 2 steps ahead. Cost +32 VGPR -> launch_bounds(256,3),
// GRID_B 768 (3 blocks/CU). In-flight gathers/CU: 3x2 vs 4x1.
// All else identical to R17 (537us): bond_out||atom_msg fused (512/1536
// split), Xbf bf16 gather source + bf16 residual, GRID_A=1024, deferred
// f32->bf16 pack, esyn = A*xb + B*Xbf[g0] + C*Xbf[g1], LDS-staged tiles,
// LDS-transposed coalesced flush + fused bond BN partials, permuted layout
// p=khalf*16+g*4+j for true t=g*8+khalf*4+j, Ab+Bb+Cb bias in bond flush,
// Ub/Vb in atom_msg, bar_lds barriers, no NT hints.

#define H   128
#define NA  300000
#define NB  600000
#define EPS 1e-5f

#define NTILE_A (NA / 32)   // 9375
#define NTILE_B (NB / 32)   // 18750
#define GRID_A  1024
#define GRID_B  768
#define EGRID   2048
#define BOUT_BLKS 512
#define MSG_BLKS  1536
#define FUSED_GRID (BOUT_BLKS + MSG_BLKS)
#define LDSW    136         // padded LDS row (bf16 elems), rows 16B-aligned

typedef __attribute__((ext_vector_type(4)))  float  f32x4;
typedef __attribute__((ext_vector_type(16))) float  f32x16;
typedef __attribute__((ext_vector_type(8)))  __bf16 bfv8;
typedef __attribute__((ext_vector_type(4)))  unsigned short u16x4;
typedef __attribute__((ext_vector_type(8)))  unsigned short u16x8;

static __device__ __forceinline__ unsigned short f2bf(float f) {
    unsigned u = __float_as_uint(f);
    u = (u + 0x7fffu + ((u >> 16) & 1u)) >> 16;   // RNE
    return (unsigned short)u;
}
static __device__ __forceinline__ float bf2f(unsigned short s) {
    return __uint_as_float(((unsigned)s) << 16);
}

// LDS-only barrier: drain ds ops, leave global loads/stores in flight.
static __device__ __forceinline__ void bar_lds() {
    asm volatile("s_waitcnt lgkmcnt(0)\n\ts_barrier" ::: "memory");
}

static __device__ __forceinline__ u16x8 pack2(f32x4 a, f32x4 b) {
    u16x8 w;
#pragma unroll
    for (int i = 0; i < 4; i++) { w[i] = f2bf(a[i]); w[i + 4] = f2bf(b[i]); }
    return w;
}

// f32 row chunk -> bf16 MFMA fragment (lane holds 8 consecutive f32)
static __device__ __forceinline__ bfv8 load_frag(const float* __restrict__ p) {
    f32x4 a = *(const f32x4*)p, b = *(const f32x4*)(p + 4);
    bfv8 f;
#pragma unroll
    for (int i = 0; i < 4; i++) { f[i] = (__bf16)a[i]; f[i + 4] = (__bf16)b[i]; }
    return f;
}

// ------- Kernel A: Ux,Vx = X*{U,V}^T bf16 (perm, NO bias) + Xbf emission ----
__global__ __launch_bounds__(512, 4) void k_atom_gemm(
    const float* __restrict__ X,
    const float* __restrict__ Uw, const float* __restrict__ Vw,
    unsigned short* __restrict__ Uxo, unsigned short* __restrict__ Vxo,
    unsigned short* __restrict__ Xbf)
{
    __shared__ unsigned short xs[2][32 * LDSW];
    __shared__ unsigned short es[2][32 * LDSW];

    const int tid   = threadIdx.x;
    const int lane  = tid & 63;
    const int w     = tid >> 6;
    const int ng    = w & 3;
    const int pair  = w >> 2;
    const int l31   = lane & 31;
    const int khalf = lane >> 5;

    const int wrow_off = (ng * 32 + l31) * H + khalf * 8;
    const int cperm    = ng * 32 + khalf * 16;

    const float* W = pair ? Vw : Uw;
    bfv8 aw[8];
#pragma unroll
    for (int k = 0; k < 8; k++) aw[k] = load_frag(W + wrow_off + k * 16);

    const int srow = tid >> 4, sseg = tid & 15;
    const int g = tid >> 8, ft = tid & 255;
    const int frow = ft >> 3, fseg = ft & 7;
    unsigned short* O = g ? Vxo : Uxo;

    const int stride = gridDim.x;
    int t = blockIdx.x;

    f32x4 sl0, sl1;
    {
        const float* sp = X + (size_t)(t * 32 + srow) * H + sseg * 8;
        sl0 = *(const f32x4*)sp; sl1 = *(const f32x4*)(sp + 4);
        u16x8 pk = pack2(sl0, sl1);
        *(u16x8*)&xs[0][srow * LDSW + sseg * 8] = pk;
        *(u16x8*)(Xbf + (size_t)(t * 32 + srow) * H + sseg * 8) = pk;
    }
    __syncthreads();

    int p = 0;
#pragma unroll 1
    for (; t < NTILE_A; ) {
        const int tn = t + stride;
        const bool have = tn < NTILE_A;
        if (have) {
            const float* sp = X + (size_t)(tn * 32 + srow) * H + sseg * 8;
            sl0 = *(const f32x4*)sp; sl1 = *(const f32x4*)(sp + 4);
        }

        {
            const unsigned short* xrow = &xs[p][l31 * LDSW + khalf * 8];
            f32x16 acc;
#pragma unroll
            for (int i = 0; i < 16; i++) acc[i] = 0.0f;
#pragma unroll
            for (int k = 0; k < 8; k++) {
                bfv8 xf = *(const bfv8*)(xrow + k * 16);
                acc = __builtin_amdgcn_mfma_f32_32x32x16_bf16(aw[k], xf, acc, 0, 0, 0);
            }
            u16x8 o0, o1;
#pragma unroll
            for (int v = 0; v < 8; v++) { o0[v] = f2bf(acc[v]); o1[v] = f2bf(acc[v + 8]); }
            unsigned short* esw = &es[pair][l31 * LDSW + cperm];
            *(u16x8*)esw       = o0;
            *(u16x8*)(esw + 8) = o1;
        }
        bar_lds();                                            // (1) es ready

        {
            const unsigned short* esr = &es[g][frow * LDSW + fseg * 16];
            u16x8 e0 = *(const u16x8*)esr, e1 = *(const u16x8*)(esr + 8);
            const size_t fbase = (size_t)(t * 32 + frow) * H + fseg * 16;
            *(u16x8*)(O + fbase)     = e0;
            *(u16x8*)(O + fbase + 8) = e1;
        }
        if (have) {
            u16x8 pk = pack2(sl0, sl1);
            *(u16x8*)&xs[p ^ 1][srow * LDSW + sseg * 8] = pk;
            *(u16x8*)(Xbf + (size_t)(tn * 32 + srow) * H + sseg * 8) = pk;
        }
        bar_lds();                                            // (2) es free, xs ready
        p ^= 1;
        t = tn;
    }
}

// --- Kernel B: esyn = A*xb + B*Xbf[g0] + C*Xbf[g1] + (Ab+Bb+Cb)  (bf16) -----
// 2-deep gather pipeline: A/B halves, two gather reg sets; ex/ey for tile
// t+2s issued at half-t's (c), consumed one unrolled iteration later.
__global__ __launch_bounds__(256, 3) void k_bond_gemm(
    const float* __restrict__ Xb, const unsigned short* __restrict__ Xbf,
    const float* __restrict__ Aw, const float* __restrict__ Bw,
    const float* __restrict__ Cw,
    const float* __restrict__ Ab, const float* __restrict__ Bb,
    const float* __restrict__ Cb,
    const int* __restrict__ g2,
    unsigned short* __restrict__ esyn,
    float* __restrict__ psum, float* __restrict__ psq)
{
    __shared__ unsigned short ts[3][32 * LDSW];   // xb, ex, ey
    __shared__ unsigned short es[32 * LDSW];
    __shared__ float bias_s[128];

    const int tid   = threadIdx.x;
    const int lane  = tid & 63;
    const int ng    = tid >> 6;
    const int l31   = lane & 31;
    const int khalf = lane >> 5;
    const int cperm = ng * 32 + khalf * 16;

    const int wro = (ng * 32 + l31) * H + khalf * 8;
    bfv8 awA[8], awB[8], awC[8];
#pragma unroll
    for (int k = 0; k < 8; k++) {
        awA[k] = load_frag(Aw + wro + k * 16);
        awB[k] = load_frag(Bw + wro + k * 16);
        awC[k] = load_frag(Cw + wro + k * 16);
    }

    if (tid < 128) {
        const int pcol = tid;
        const int grp = pcol >> 5, r = pcol & 31, kh = r >> 4, wi = r & 15;
        const int ct = grp * 32 + (wi >> 2) * 8 + kh * 4 + (wi & 3);
        bias_s[pcol] = Ab[ct] + Bb[ct] + Cb[ct];
    }

    const int srow = tid >> 3, sseg = tid & 7;

    float fs[16], fq[16];
#pragma unroll
    for (int i = 0; i < 16; i++) { fs[i] = 0.f; fq[i] = 0.f; }

    const int stride = gridDim.x;
    const int s2 = 2 * stride;

    // Xb staging (1-deep, alternates halves); gather sets A/B (2-deep)
    f32x4 sxb[4];
    u16x8 reA0, reA1, ryA0, ryA1;
    u16x8 reB0, reB1, ryB0, ryB1;
    int2 ggA, ggB;   // g2 rows for the NEXT A/B gather issues

    int tA = blockIdx.x;
    int tB = tA + stride;

#define LOAD_XB(T)                                                             \
    {                                                                          \
        const float* sp_ = Xb + (size_t)((T) * 32 + srow) * H + sseg * 16;     \
        _Pragma("unroll") for (int i_ = 0; i_ < 4; i_++)                       \
            sxb[i_] = *(const f32x4*)(sp_ + 4 * i_);                           \
    }
#define GATHER(G, E0, E1, Y0, Y1)                                              \
    {                                                                          \
        const unsigned short* ep_ = Xbf + (size_t)(G).x * H + sseg * 16;       \
        E0 = *(const u16x8*)ep_;  E1 = *(const u16x8*)(ep_ + 8);               \
        const unsigned short* yp_ = Xbf + (size_t)(G).y * H + sseg * 16;       \
        Y0 = *(const u16x8*)yp_;  Y1 = *(const u16x8*)(yp_ + 8);               \
    }
#define G2ROW(T) (*(const int2*)(g2 + 2 * (size_t)((T) * 32 + srow)))

    {   // prologue
        int2 g0 = G2ROW(tA);
        LOAD_XB(tA);
        GATHER(g0, reA0, reA1, ryA0, ryA1);
        if (tB < NTILE_B) { int2 g1 = G2ROW(tB); GATHER(g1, reB0, reB1, ryB0, ryB1); }
        if (tA + s2 < NTILE_B) ggA = G2ROW(tA + s2);
        if (tB + s2 < NTILE_B) ggB = G2ROW(tB + s2);
    }

#pragma unroll 1
    for (; tA < NTILE_B; ) {
        // ================= half A: process tile tA with gather set A =========
        {
            const int off = srow * LDSW + sseg * 16;
            *(u16x8*)&ts[0][off]     = pack2(sxb[0], sxb[1]);
            *(u16x8*)&ts[0][off + 8] = pack2(sxb[2], sxb[3]);
            *(u16x8*)&ts[1][off]     = reA0; *(u16x8*)&ts[1][off + 8] = reA1;
            *(u16x8*)&ts[2][off]     = ryA0; *(u16x8*)&ts[2][off + 8] = ryA1;
        }
        bar_lds();

        if (tB < NTILE_B) LOAD_XB(tB);                      // Xb for half B
        if (tA + s2 < NTILE_B) {                            // re-arm set A (2-deep)
            GATHER(ggA, reA0, reA1, ryA0, ryA1);
            if (tA + 2 * s2 < NTILE_B) ggA = G2ROW(tA + 2 * s2);
        }

        {
            const unsigned short* x0 = &ts[0][l31 * LDSW + khalf * 8];
            const unsigned short* x1 = &ts[1][l31 * LDSW + khalf * 8];
            const unsigned short* x2 = &ts[2][l31 * LDSW + khalf * 8];
            f32x16 acc;
#pragma unroll
            for (int i = 0; i < 16; i++) acc[i] = 0.0f;
#pragma unroll
            for (int k = 0; k < 8; k++)
                acc = __builtin_amdgcn_mfma_f32_32x32x16_bf16(awA[k], *(const bfv8*)(x0 + k * 16), acc, 0, 0, 0);
#pragma unroll
            for (int k = 0; k < 8; k++)
                acc = __builtin_amdgcn_mfma_f32_32x32x16_bf16(awB[k], *(const bfv8*)(x1 + k * 16), acc, 0, 0, 0);
#pragma unroll
            for (int k = 0; k < 8; k++)
                acc = __builtin_amdgcn_mfma_f32_32x32x16_bf16(awC[k], *(const bfv8*)(x2 + k * 16), acc, 0, 0, 0);
            u16x8 o0, o1;
#pragma unroll
            for (int v = 0; v < 8; v++) { o0[v] = f2bf(acc[v]); o1[v] = f2bf(acc[v + 8]); }
            unsigned short* esw = &es[l31 * LDSW + cperm];
            *(u16x8*)esw       = o0;
            *(u16x8*)(esw + 8) = o1;
        }
        bar_lds();

        {
            const unsigned short* esr = &es[srow * LDSW + sseg * 16];
            u16x8 e0 = *(const u16x8*)esr, e1 = *(const u16x8*)(esr + 8);
            const float* bp = bias_s + sseg * 16;
            u16x8 w0, w1;
#pragma unroll
            for (int i = 0; i < 8; i++) {
                float v = bf2f(e0[i]) + bp[i];
                w0[i] = f2bf(v); fs[i] += v; fq[i] += v * v;
            }
#pragma unroll
            for (int i = 0; i < 8; i++) {
                float v = bf2f(e1[i]) + bp[8 + i];
                w1[i] = f2bf(v); fs[8 + i] += v; fq[8 + i] += v * v;
            }
            unsigned short* op = esyn + (size_t)(tA * 32 + srow) * H + sseg * 16;
            *(u16x8*)op       = w0;
            *(u16x8*)(op + 8) = w1;
        }

        // ================= half B: process tile tB with gather set B =========
        if (tB < NTILE_B) {
            bar_lds();   // es free before overwrite (half A flush reads done)
            {
                const int off = srow * LDSW + sseg * 16;
                *(u16x8*)&ts[0][off]     = pack2(sxb[0], sxb[1]);
                *(u16x8*)&ts[0][off + 8] = pack2(sxb[2], sxb[3]);
                *(u16x8*)&ts[1][off]     = reB0; *(u16x8*)&ts[1][off + 8] = reB1;
                *(u16x8*)&ts[2][off]     = ryB0; *(u16x8*)&ts[2][off + 8] = ryB1;
            }
            bar_lds();

            if (tA + s2 < NTILE_B) LOAD_XB(tA + s2);        // Xb for next half A
            if (tB + s2 < NTILE_B) {                        // re-arm set B
                GATHER(ggB, reB0, reB1, ryB0, ryB1);
                if (tB + 2 * s2 < NTILE_B) ggB = G2ROW(tB + 2 * s2);
            }

            {
                const unsigned short* x0 = &ts[0][l31 * LDSW + khalf * 8];
                const unsigned short* x1 = &ts[1][l31 * LDSW + khalf * 8];
                const unsigned short* x2 = &ts[2][l31 * LDSW + khalf * 8];
                f32x16 acc;
#pragma unroll
                for (int i = 0; i < 16; i++) acc[i] = 0.0f;
#pragma unroll
                for (int k = 0; k < 8; k++)
                    acc = __builtin_amdgcn_mfma_f32_32x32x16_bf16(awA[k], *(const bfv8*)(x0 + k * 16), acc, 0, 0, 0);
#pragma unroll
                for (int k = 0; k < 8; k++)
                    acc = __builtin_amdgcn_mfma_f32_32x32x16_bf16(awB[k], *(const bfv8*)(x1 + k * 16), acc, 0, 0, 0);
#pragma unroll
                for (int k = 0; k < 8; k++)
                    acc = __builtin_amdgcn_mfma_f32_32x32x16_bf16(awC[k], *(const bfv8*)(x2 + k * 16), acc, 0, 0, 0);
                u16x8 o0, o1;
#pragma unroll
                for (int v = 0; v < 8; v++) { o0[v] = f2bf(acc[v]); o1[v] = f2bf(acc[v + 8]); }
                unsigned short* esw = &es[l31 * LDSW + cperm];
                *(u16x8*)esw       = o0;
                *(u16x8*)(esw + 8) = o1;
            }
            bar_lds();

            {
                const unsigned short* esr = &es[srow * LDSW + sseg * 16];
                u16x8 e0 = *(const u16x8*)esr, e1 = *(const u16x8*)(esr + 8);
                const float* bp = bias_s + sseg * 16;
                u16x8 w0, w1;
#pragma unroll
                for (int i = 0; i < 8; i++) {
                    float v = bf2f(e0[i]) + bp[i];
                    w0[i] = f2bf(v); fs[i] += v; fq[i] += v * v;
                }
#pragma unroll
                for (int i = 0; i < 8; i++) {
                    float v = bf2f(e1[i]) + bp[8 + i];
                    w1[i] = f2bf(v); fs[8 + i] += v; fq[8 + i] += v * v;
                }
                unsigned short* op = esyn + (size_t)(tB * 32 + srow) * H + sseg * 16;
                *(u16x8*)op       = w0;
                *(u16x8*)(op + 8) = w1;
            }
            bar_lds();   // ts free before next half A's writes
        }
        tA += s2; tB += s2;
    }
#undef LOAD_XB
#undef GATHER
#undef G2ROW

    // deterministic per-block stats reduction
    float* red = (float*)es;
    for (int i = 0; i < 16; i++) {
        __syncthreads();
        red[tid] = fs[i]; red[256 + tid] = fq[i];
        __syncthreads();
        if (tid < 8) {
            float S = 0.f, Q = 0.f;
            for (int r = 0; r < 32; r++) { S += red[r * 8 + tid]; Q += red[256 + r * 8 + tid]; }
            psum[(size_t)blockIdx.x * H + tid * 16 + i] = S;
            psq [(size_t)blockIdx.x * H + tid * 16 + i] = Q;
        }
    }
}

// ---------------- Kernel C: reduce partials -> scale/shift (permuted index) --
__global__ void k_bn_stats(const float* __restrict__ psum, const float* __restrict__ psq,
                           int nblk, float invN,
                           const float* __restrict__ gamma, const float* __restrict__ beta,
                           float* __restrict__ scale, float* __restrict__ shift)
{
    __shared__ float ls[256], lq[256];
    const int c = blockIdx.x;                 // permuted column index
    float s = 0.f, q = 0.f;
    for (int i = threadIdx.x; i < nblk; i += 256) {
        s += psum[(size_t)i * H + c];
        q += psq [(size_t)i * H + c];
    }
    ls[threadIdx.x] = s; lq[threadIdx.x] = q;
    __syncthreads();
    for (int off = 128; off > 0; off >>= 1) {
        if ((int)threadIdx.x < off) {
            ls[threadIdx.x] += ls[threadIdx.x + off];
            lq[threadIdx.x] += lq[threadIdx.x + off];
        }
        __syncthreads();
    }
    if (threadIdx.x == 0) {
        const int r = c & 31, kh = r >> 4, wi = r & 15;
        const int ct = (c & ~31) + (wi >> 2) * 8 + kh * 4 + (wi & 3);
        float mean = ls[0] * invN;
        float var  = lq[0] * invN - mean * mean;
        float sc   = gamma[ct] * rsqrtf(var + EPS);
        scale[c] = sc;
        shift[c] = beta[ct] - mean * sc;
    }
}

// ------- Fused: bond finalize (blocks 0..511)  ||  atom message (512..2047) --
__global__ __launch_bounds__(256) void k_bout_amsg(
    const unsigned short* __restrict__ esyn,
    float* __restrict__ out_bond,
    const float* __restrict__ scale, const float* __restrict__ shift,
    const unsigned short* __restrict__ Ux,
    const unsigned short* __restrict__ Vx,
    const int* __restrict__ adj,
    const int* __restrict__ abadj,
    const float* __restrict__ Ub, const float* __restrict__ Vb,
    unsigned short* __restrict__ syn_a,
    float* __restrict__ psum, float* __restrict__ psq)
{
    __shared__ float ls[256][8], lq[256][8];

    if (blockIdx.x < BOUT_BLKS) {
        // -------- bond finalize: esyn(bf16,perm) -> relu(bn) f32 true cols --
        const size_t total  = (size_t)NB * (H / 8);
        const size_t stride = (size_t)BOUT_BLKS * 256;
        const int c0 = (threadIdx.x & 15) * 8;
        const f32x4 sc0 = *(const f32x4*)(scale + c0), sc1 = *(const f32x4*)(scale + c0 + 4);
        const f32x4 sh0 = *(const f32x4*)(shift + c0), sh1 = *(const f32x4*)(shift + c0 + 4);
        const int tc0 = (c0 & ~31) + (((c0 >> 2) & 3) * 8) + ((c0 >> 4) & 1) * 4;
        const int tc1 = tc0 + 8;
        for (size_t i = (size_t)blockIdx.x * 256 + threadIdx.x; i < total; i += stride) {
            u16x8 v = ((const u16x8*)esyn)[i];
            const size_t row = i >> 4;
            f32x4 o0, o1;
#pragma unroll
            for (int j = 0; j < 4; j++) {
                o0[j] = fmaxf(bf2f(v[j])     * sc0[j] + sh0[j], 0.0f);
                o1[j] = fmaxf(bf2f(v[j + 4]) * sc1[j] + sh1[j], 0.0f);
            }
            float* yp = out_bond + row * H;
            *(f32x4*)(yp + tc0) = o0;
            *(f32x4*)(yp + tc1) = o1;
        }
        return;
    }

    // -------- atom message: syn_a = (Ux+Ub) + sum_k sig(esyn[b])*(Vx[a]+Vb) --
    const int bid = blockIdx.x - BOUT_BLKS;
    const int cg = threadIdx.x & 15;
    const int rh = threadIdx.x >> 4;
    const int c0 = cg * 8;                       // permuted chunk base
    const int tc0 = (c0 & ~31) + (((c0 >> 2) & 3) * 8) + ((c0 >> 4) & 1) * 4;
    const f32x4 ub0 = *(const f32x4*)(Ub + tc0), ub1 = *(const f32x4*)(Ub + tc0 + 8);
    const f32x4 vb0 = *(const f32x4*)(Vb + tc0), vb1 = *(const f32x4*)(Vb + tc0 + 8);

    float s[8], q[8];
#pragma unroll
    for (int j = 0; j < 8; j++) { s[j] = 0.f; q[j] = 0.f; }

    const int rstride = MSG_BLKS * 16;
    int r = bid * 16 + rh;

    int2 A[3], Bv[3];
    if (r < NA) {
#pragma unroll
        for (int p = 0; p < 3; p++) {
            A[p]  = *(const int2*)(adj   + (size_t)r * 6 + 2 * p);
            Bv[p] = *(const int2*)(abadj + (size_t)r * 6 + 2 * p);
        }
    }

#pragma unroll 1
    for (; r < NA; ) {
        const int rn = r + rstride;

        const int ai[6] = {A[0].x, A[0].y, A[1].x, A[1].y, A[2].x, A[2].y};
        const int bi[6] = {Bv[0].x, Bv[0].y, Bv[1].x, Bv[1].y, Bv[2].x, Bv[2].y};

        u16x8 uv = *(const u16x8*)(Ux + (size_t)r * H + c0);

        if (rn < NA) {
#pragma unroll
            for (int p = 0; p < 3; p++) {
                A[p]  = *(const int2*)(adj   + (size_t)rn * 6 + 2 * p);
                Bv[p] = *(const int2*)(abadj + (size_t)rn * 6 + 2 * p);
            }
        }

        float v[8];
#pragma unroll
        for (int j = 0; j < 4; j++) {
            v[j]     = bf2f(uv[j])     + ub0[j];
            v[j + 4] = bf2f(uv[j + 4]) + ub1[j];
        }
#pragma unroll
        for (int k = 0; k < 6; k++) {
            u16x8 vx = *(const u16x8*)(Vx   + (size_t)ai[k] * H + c0);
            u16x8 es = *(const u16x8*)(esyn + (size_t)bi[k] * H + c0);
#pragma unroll
            for (int j = 0; j < 4; j++) {
                float g0 = 1.0f / (1.0f + __expf(-bf2f(es[j])));
                float g1 = 1.0f / (1.0f + __expf(-bf2f(es[j + 4])));
                v[j]     += g0 * (bf2f(vx[j])     + vb0[j]);
                v[j + 4] += g1 * (bf2f(vx[j + 4]) + vb1[j]);
            }
        }
        u16x8 ov;
#pragma unroll
        for (int j = 0; j < 8; j++) ov[j] = f2bf(v[j]);
        *(u16x8*)(syn_a + (size_t)r * H + c0) = ov;
#pragma unroll
        for (int j = 0; j < 8; j++) { s[j] += v[j]; q[j] += v[j] * v[j]; }

        r = rn;
    }

#pragma unroll
    for (int j = 0; j < 8; j++) { ls[threadIdx.x][j] = s[j]; lq[threadIdx.x][j] = q[j]; }
    __syncthreads();
    if (threadIdx.x < 128) {
        const int c = threadIdx.x, g = c >> 3, j = c & 7;
        float S = 0.f, Q = 0.f;
        for (int rg = 0; rg < 16; rg++) { S += ls[rg * 16 + g][j]; Q += lq[rg * 16 + g][j]; }
        psum[(size_t)bid * H + c] = S;
        psq [(size_t)bid * H + c] = Q;
    }
}

// -------- Kernel F: atom finalize: bn(syn_a)+relu + residual (Xbf bf16) ------
__global__ __launch_bounds__(256) void k_atom_out(const unsigned short* __restrict__ syn,
                                                  const unsigned short* __restrict__ xbf,
                                                  float* __restrict__ y,
                                                  const float* __restrict__ scale,
                                                  const float* __restrict__ shift)
{
    const size_t total  = (size_t)NA * (H / 8);
    const size_t stride = (size_t)gridDim.x * 256;
    const int c0 = (threadIdx.x & 15) * 8;       // permuted chunk base
    const f32x4 sc0 = *(const f32x4*)(scale + c0), sc1 = *(const f32x4*)(scale + c0 + 4);
    const f32x4 sh0 = *(const f32x4*)(shift + c0), sh1 = *(const f32x4*)(shift + c0 + 4);
    const int tc0 = (c0 & ~31) + (((c0 >> 2) & 3) * 8) + ((c0 >> 4) & 1) * 4;
    const int tc1 = tc0 + 8;
    for (size_t i = (size_t)blockIdx.x * 256 + threadIdx.x; i < total; i += stride) {
        u16x8 v = ((const u16x8*)syn)[i];
        const size_t row = i >> 4;
        const unsigned short* xp = xbf + row * H;
        u16x4 x0 = *(const u16x4*)(xp + tc0);
        u16x4 x1 = *(const u16x4*)(xp + tc1);
        f32x4 o0, o1;
#pragma unroll
        for (int j = 0; j < 4; j++) {
            o0[j] = fmaxf(bf2f(v[j])     * sc0[j] + sh0[j], 0.0f) + bf2f(x0[j]);
            o1[j] = fmaxf(bf2f(v[j + 4]) * sc1[j] + sh1[j], 0.0f) + bf2f(x1[j]);
        }
        float* yp = y + row * H;
        *(f32x4*)(yp + tc0) = o0;
        *(f32x4*)(yp + tc1) = o1;
    }
}

extern "C" void kernel_launch(void* const* d_in, const int* in_sizes, int n_in,
                              void* d_out, int out_size, void* d_ws, size_t ws_size,
                              hipStream_t stream)
{
    const float* X     = (const float*)d_in[0];
    const float* Xb    = (const float*)d_in[1];
    const int*   adj   = (const int*)d_in[2];
    const int*   abadj = (const int*)d_in[3];
    const int*   g2    = (const int*)d_in[4];
    const float* Uw = (const float*)d_in[5],  *Ub = (const float*)d_in[6];
    const float* Vw = (const float*)d_in[7],  *Vb = (const float*)d_in[8];
    const float* Aw = (const float*)d_in[9],  *Ab = (const float*)d_in[10];
    const float* Bw = (const float*)d_in[11], *Bb = (const float*)d_in[12];
    const float* Cw = (const float*)d_in[13], *Cb = (const float*)d_in[14];
    const float* gb = (const float*)d_in[15], *bb = (const float*)d_in[16];
    const float* ga = (const float*)d_in[17], *ba = (const float*)d_in[18];

    float* out_atom = (float*)d_out;
    float* out_bond = out_atom + (size_t)NA * H;

    char* ws = (char*)d_ws;
    size_t o = 0;
    unsigned short* Ux    = (unsigned short*)(ws + o); o += (size_t)NA * H * 2;
    unsigned short* Vx    = (unsigned short*)(ws + o); o += (size_t)NA * H * 2;
    unsigned short* Xbf   = (unsigned short*)(ws + o); o += (size_t)NA * H * 2;
    unsigned short* esyn  = (unsigned short*)(ws + o); o += (size_t)NB * H * 2;
    unsigned short* syn_a = (unsigned short*)(ws + o); o += (size_t)NA * H * 2;
    float* psum_b = (float*)(ws + o);  o += (size_t)EGRID * H * 4;
    float* psq_b  = (float*)(ws + o);  o += (size_t)EGRID * H * 4;
    float* psum_a = (float*)(ws + o);  o += (size_t)EGRID * H * 4;
    float* psq_a  = (float*)(ws + o);  o += (size_t)EGRID * H * 4;
    float* scale_b = (float*)(ws + o); o += 512;
    float* shift_b = (float*)(ws + o); o += 512;
    float* scale_a = (float*)(ws + o); o += 512;
    float* shift_a = (float*)(ws + o); o += 512;
    (void)o; (void)ws_size; (void)in_sizes; (void)n_in; (void)out_size;

    k_atom_gemm<<<GRID_A, 512, 0, stream>>>(X, Uw, Vw, Ux, Vx, Xbf);
    k_bond_gemm<<<GRID_B, 256, 0, stream>>>(Xb, Xbf, Aw, Bw, Cw, Ab, Bb, Cb, g2,
                                            esyn, psum_b, psq_b);
    k_bn_stats<<<H, 256, 0, stream>>>(psum_b, psq_b, GRID_B, 1.0f / NB, gb, bb, scale_b, shift_b);
    k_bout_amsg<<<FUSED_GRID, 256, 0, stream>>>(esyn, out_bond, scale_b, shift_b,
                                                Ux, Vx, adj, abadj, Ub, Vb,
                                                syn_a, psum_a, psq_a);
    k_bn_stats<<<H, 256, 0, stream>>>(psum_a, psq_a, MSG_BLKS, 1.0f / NA, ga, ba, scale_a, shift_a);
    k_atom_out<<<EGRID, 256, 0, stream>>>(syn_a, Xbf, out_atom, scale_a, shift_a);
}

// Round 19
// 536.321 us; speedup vs baseline: 1.3691x; 1.3691x over previous
//
#include <hip/hip_runtime.h>
#include <hip/hip_bf16.h>

// ConvNetLayer fused pipeline, MI355X (gfx950). Round 19 = R17 exact revert.
//
// R18's 2-deep gather pipeline REGRESSED (bond_gemm 200->364us, FETCH
// 461->692MB): gathers issued 2 iterations ahead get evicted from L2 before
// consumption (per-CU outstanding gather footprint tripled, L2 stayed 4MiB)
// -> lines fetched twice. Reverted.
// R17 (537us, best): bond_out||atom_msg fused (512/1536 split), Xbf bf16
// gather source + bf16 residual, GRID_A=1024, deferred f32->bf16 pack in
// bond_gemm, esyn = A*xb + B*Xbf[g0] + C*Xbf[g1] (3 MFMA chains),
// LDS-staged tiles, LDS-transposed coalesced flush + fused bond BN
// partials, permuted layout p=khalf*16+g*4+j for true t=g*8+khalf*4+j,
// Ab+Bb+Cb bias in bond flush, Ub/Vb in atom_msg, GRID_B=1024, bar_lds
// barriers, no NT hints.

#define H   128
#define NA  300000
#define NB  600000
#define EPS 1e-5f

#define NTILE_A (NA / 32)   // 9375
#define NTILE_B (NB / 32)   // 18750
#define GRID_A  1024
#define GRID_B  1024
#define EGRID   2048
#define BOUT_BLKS 512
#define MSG_BLKS  1536
#define FUSED_GRID (BOUT_BLKS + MSG_BLKS)
#define LDSW    136         // padded LDS row (bf16 elems), rows 16B-aligned

typedef __attribute__((ext_vector_type(4)))  float  f32x4;
typedef __attribute__((ext_vector_type(16))) float  f32x16;
typedef __attribute__((ext_vector_type(8)))  __bf16 bfv8;
typedef __attribute__((ext_vector_type(4)))  unsigned short u16x4;
typedef __attribute__((ext_vector_type(8)))  unsigned short u16x8;

static __device__ __forceinline__ unsigned short f2bf(float f) {
    unsigned u = __float_as_uint(f);
    u = (u + 0x7fffu + ((u >> 16) & 1u)) >> 16;   // RNE
    return (unsigned short)u;
}
static __device__ __forceinline__ float bf2f(unsigned short s) {
    return __uint_as_float(((unsigned)s) << 16);
}

// LDS-only barrier: drain ds ops, leave global loads/stores in flight.
static __device__ __forceinline__ void bar_lds() {
    asm volatile("s_waitcnt lgkmcnt(0)\n\ts_barrier" ::: "memory");
}

static __device__ __forceinline__ u16x8 pack2(f32x4 a, f32x4 b) {
    u16x8 w;
#pragma unroll
    for (int i = 0; i < 4; i++) { w[i] = f2bf(a[i]); w[i + 4] = f2bf(b[i]); }
    return w;
}

// f32 row chunk -> bf16 MFMA fragment (lane holds 8 consecutive f32)
static __device__ __forceinline__ bfv8 load_frag(const float* __restrict__ p) {
    f32x4 a = *(const f32x4*)p, b = *(const f32x4*)(p + 4);
    bfv8 f;
#pragma unroll
    for (int i = 0; i < 4; i++) { f[i] = (__bf16)a[i]; f[i + 4] = (__bf16)b[i]; }
    return f;
}

// ------- Kernel A: Ux,Vx = X*{U,V}^T bf16 (perm, NO bias) + Xbf emission ----
__global__ __launch_bounds__(512, 4) void k_atom_gemm(
    const float* __restrict__ X,
    const float* __restrict__ Uw, const float* __restrict__ Vw,
    unsigned short* __restrict__ Uxo, unsigned short* __restrict__ Vxo,
    unsigned short* __restrict__ Xbf)
{
    __shared__ unsigned short xs[2][32 * LDSW];
    __shared__ unsigned short es[2][32 * LDSW];

    const int tid   = threadIdx.x;
    const int lane  = tid & 63;
    const int w     = tid >> 6;
    const int ng    = w & 3;
    const int pair  = w >> 2;
    const int l31   = lane & 31;
    const int khalf = lane >> 5;

    const int wrow_off = (ng * 32 + l31) * H + khalf * 8;
    const int cperm    = ng * 32 + khalf * 16;

    const float* W = pair ? Vw : Uw;
    bfv8 aw[8];
#pragma unroll
    for (int k = 0; k < 8; k++) aw[k] = load_frag(W + wrow_off + k * 16);

    const int srow = tid >> 4, sseg = tid & 15;
    const int g = tid >> 8, ft = tid & 255;
    const int frow = ft >> 3, fseg = ft & 7;
    unsigned short* O = g ? Vxo : Uxo;

    const int stride = gridDim.x;
    int t = blockIdx.x;

    f32x4 sl0, sl1;
    {
        const float* sp = X + (size_t)(t * 32 + srow) * H + sseg * 8;
        sl0 = *(const f32x4*)sp; sl1 = *(const f32x4*)(sp + 4);
        u16x8 pk = pack2(sl0, sl1);
        *(u16x8*)&xs[0][srow * LDSW + sseg * 8] = pk;
        *(u16x8*)(Xbf + (size_t)(t * 32 + srow) * H + sseg * 8) = pk;
    }
    __syncthreads();

    int p = 0;
#pragma unroll 1
    for (; t < NTILE_A; ) {
        const int tn = t + stride;
        const bool have = tn < NTILE_A;
        if (have) {
            const float* sp = X + (size_t)(tn * 32 + srow) * H + sseg * 8;
            sl0 = *(const f32x4*)sp; sl1 = *(const f32x4*)(sp + 4);
        }

        {
            const unsigned short* xrow = &xs[p][l31 * LDSW + khalf * 8];
            f32x16 acc;
#pragma unroll
            for (int i = 0; i < 16; i++) acc[i] = 0.0f;
#pragma unroll
            for (int k = 0; k < 8; k++) {
                bfv8 xf = *(const bfv8*)(xrow + k * 16);
                acc = __builtin_amdgcn_mfma_f32_32x32x16_bf16(aw[k], xf, acc, 0, 0, 0);
            }
            u16x8 o0, o1;
#pragma unroll
            for (int v = 0; v < 8; v++) { o0[v] = f2bf(acc[v]); o1[v] = f2bf(acc[v + 8]); }
            unsigned short* esw = &es[pair][l31 * LDSW + cperm];
            *(u16x8*)esw       = o0;
            *(u16x8*)(esw + 8) = o1;
        }
        bar_lds();                                            // (1) es ready

        {
            const unsigned short* esr = &es[g][frow * LDSW + fseg * 16];
            u16x8 e0 = *(const u16x8*)esr, e1 = *(const u16x8*)(esr + 8);
            const size_t fbase = (size_t)(t * 32 + frow) * H + fseg * 16;
            *(u16x8*)(O + fbase)     = e0;
            *(u16x8*)(O + fbase + 8) = e1;
        }
        if (have) {
            u16x8 pk = pack2(sl0, sl1);
            *(u16x8*)&xs[p ^ 1][srow * LDSW + sseg * 8] = pk;
            *(u16x8*)(Xbf + (size_t)(tn * 32 + srow) * H + sseg * 8) = pk;
        }
        bar_lds();                                            // (2) es free, xs ready
        p ^= 1;
        t = tn;
    }
}

// --- Kernel B: esyn = A*xb + B*Xbf[g0] + C*Xbf[g1] + (Ab+Bb+Cb)  (bf16) -----
__global__ __launch_bounds__(256, 2) void k_bond_gemm(
    const float* __restrict__ Xb, const unsigned short* __restrict__ Xbf,
    const float* __restrict__ Aw, const float* __restrict__ Bw,
    const float* __restrict__ Cw,
    const float* __restrict__ Ab, const float* __restrict__ Bb,
    const float* __restrict__ Cb,
    const int* __restrict__ g2,
    unsigned short* __restrict__ esyn,
    float* __restrict__ psum, float* __restrict__ psq)
{
    __shared__ unsigned short ts[3][32 * LDSW];   // xb, ex, ey
    __shared__ unsigned short es[32 * LDSW];
    __shared__ float bias_s[128];

    const int tid   = threadIdx.x;
    const int lane  = tid & 63;
    const int ng    = tid >> 6;
    const int l31   = lane & 31;
    const int khalf = lane >> 5;
    const int cperm = ng * 32 + khalf * 16;

    const int wro = (ng * 32 + l31) * H + khalf * 8;
    bfv8 awA[8], awB[8], awC[8];
#pragma unroll
    for (int k = 0; k < 8; k++) {
        awA[k] = load_frag(Aw + wro + k * 16);
        awB[k] = load_frag(Bw + wro + k * 16);
        awC[k] = load_frag(Cw + wro + k * 16);
    }

    if (tid < 128) {
        const int pcol = tid;
        const int grp = pcol >> 5, r = pcol & 31, kh = r >> 4, wi = r & 15;
        const int ct = grp * 32 + (wi >> 2) * 8 + kh * 4 + (wi & 3);
        bias_s[pcol] = Ab[ct] + Bb[ct] + Cb[ct];
    }

    const int srow = tid >> 3, sseg = tid & 7;

    float fs[16], fq[16];
#pragma unroll
    for (int i = 0; i < 16; i++) { fs[i] = 0.f; fq[i] = 0.f; }

    const int stride = gridDim.x;
    int t = blockIdx.x;

    f32x4 sxb[4];
    u16x8 re0, re1, ry0, ry1;
    int2 gg;

    {   // prologue: raw-load tile t
        int2 g0 = *(const int2*)(g2 + 2 * (size_t)(t * 32 + srow));
        const float* sp = Xb + (size_t)(t * 32 + srow) * H + sseg * 16;
#pragma unroll
        for (int i = 0; i < 4; i++) sxb[i] = *(const f32x4*)(sp + 4 * i);
        const unsigned short* ep = Xbf + (size_t)g0.x * H + sseg * 16;
        re0 = *(const u16x8*)ep;  re1 = *(const u16x8*)(ep + 8);
        const unsigned short* yp = Xbf + (size_t)g0.y * H + sseg * 16;
        ry0 = *(const u16x8*)yp;  ry1 = *(const u16x8*)(yp + 8);
        const int tnx = t + stride;
        if (tnx < NTILE_B) gg = *(const int2*)(g2 + 2 * (size_t)(tnx * 32 + srow));
    }

#pragma unroll 1
    for (; t < NTILE_B; ) {
        const int tn = t + stride;
        const bool have = tn < NTILE_B;

        // (a) pack (vmcnt wait lands here, covered by prev iter's d/e/f)
        {
            const int off = srow * LDSW + sseg * 16;
            *(u16x8*)&ts[0][off]     = pack2(sxb[0], sxb[1]);
            *(u16x8*)&ts[0][off + 8] = pack2(sxb[2], sxb[3]);
            *(u16x8*)&ts[1][off]     = re0; *(u16x8*)&ts[1][off + 8] = re1;
            *(u16x8*)&ts[2][off]     = ry0; *(u16x8*)&ts[2][off + 8] = ry1;
        }
        bar_lds();                                            // (b) tiles ready

        // (c) issue next tile's RAW loads
        if (have) {
            const float* sp = Xb + (size_t)(tn * 32 + srow) * H + sseg * 16;
#pragma unroll
            for (int i = 0; i < 4; i++) sxb[i] = *(const f32x4*)(sp + 4 * i);
            const unsigned short* ep = Xbf + (size_t)gg.x * H + sseg * 16;
            re0 = *(const u16x8*)ep;  re1 = *(const u16x8*)(ep + 8);
            const unsigned short* yp = Xbf + (size_t)gg.y * H + sseg * 16;
            ry0 = *(const u16x8*)yp;  ry1 = *(const u16x8*)(yp + 8);
            const int tnn = tn + stride;
            if (tnn < NTILE_B) gg = *(const int2*)(g2 + 2 * (size_t)(tnn * 32 + srow));
        }

        // (d) 3 MFMA chains -> raw bf16 acc -> es
        {
            const unsigned short* x0 = &ts[0][l31 * LDSW + khalf * 8];
            const unsigned short* x1 = &ts[1][l31 * LDSW + khalf * 8];
            const unsigned short* x2 = &ts[2][l31 * LDSW + khalf * 8];
            f32x16 acc;
#pragma unroll
            for (int i = 0; i < 16; i++) acc[i] = 0.0f;
#pragma unroll
            for (int k = 0; k < 8; k++)
                acc = __builtin_amdgcn_mfma_f32_32x32x16_bf16(awA[k], *(const bfv8*)(x0 + k * 16), acc, 0, 0, 0);
#pragma unroll
            for (int k = 0; k < 8; k++)
                acc = __builtin_amdgcn_mfma_f32_32x32x16_bf16(awB[k], *(const bfv8*)(x1 + k * 16), acc, 0, 0, 0);
#pragma unroll
            for (int k = 0; k < 8; k++)
                acc = __builtin_amdgcn_mfma_f32_32x32x16_bf16(awC[k], *(const bfv8*)(x2 + k * 16), acc, 0, 0, 0);
            u16x8 o0, o1;
#pragma unroll
            for (int v = 0; v < 8; v++) { o0[v] = f2bf(acc[v]); o1[v] = f2bf(acc[v + 8]); }
            unsigned short* esw = &es[l31 * LDSW + cperm];
            *(u16x8*)esw       = o0;
            *(u16x8*)(esw + 8) = o1;
        }
        bar_lds();                                            // (e) es ready, tiles free

        // (f) flush: bias + stats + coalesced store
        {
            const unsigned short* esr = &es[srow * LDSW + sseg * 16];
            u16x8 e0 = *(const u16x8*)esr, e1 = *(const u16x8*)(esr + 8);
            const float* bp = bias_s + sseg * 16;
            u16x8 w0, w1;
#pragma unroll
            for (int i = 0; i < 8; i++) {
                float v = bf2f(e0[i]) + bp[i];
                w0[i] = f2bf(v); fs[i] += v; fq[i] += v * v;
            }
#pragma unroll
            for (int i = 0; i < 8; i++) {
                float v = bf2f(e1[i]) + bp[8 + i];
                w1[i] = f2bf(v); fs[8 + i] += v; fq[8 + i] += v * v;
            }
            unsigned short* op = esyn + (size_t)(t * 32 + srow) * H + sseg * 16;
            *(u16x8*)op       = w0;
            *(u16x8*)(op + 8) = w1;
        }
        t = tn;
    }

    // deterministic per-block stats reduction
    float* red = (float*)es;
    for (int i = 0; i < 16; i++) {
        __syncthreads();
        red[tid] = fs[i]; red[256 + tid] = fq[i];
        __syncthreads();
        if (tid < 8) {
            float S = 0.f, Q = 0.f;
            for (int r = 0; r < 32; r++) { S += red[r * 8 + tid]; Q += red[256 + r * 8 + tid]; }
            psum[(size_t)blockIdx.x * H + tid * 16 + i] = S;
            psq [(size_t)blockIdx.x * H + tid * 16 + i] = Q;
        }
    }
}

// ---------------- Kernel C: reduce partials -> scale/shift (permuted index) --
__global__ void k_bn_stats(const float* __restrict__ psum, const float* __restrict__ psq,
                           int nblk, float invN,
                           const float* __restrict__ gamma, const float* __restrict__ beta,
                           float* __restrict__ scale, float* __restrict__ shift)
{
    __shared__ float ls[256], lq[256];
    const int c = blockIdx.x;                 // permuted column index
    float s = 0.f, q = 0.f;
    for (int i = threadIdx.x; i < nblk; i += 256) {
        s += psum[(size_t)i * H + c];
        q += psq [(size_t)i * H + c];
    }
    ls[threadIdx.x] = s; lq[threadIdx.x] = q;
    __syncthreads();
    for (int off = 128; off > 0; off >>= 1) {
        if ((int)threadIdx.x < off) {
            ls[threadIdx.x] += ls[threadIdx.x + off];
            lq[threadIdx.x] += lq[threadIdx.x + off];
        }
        __syncthreads();
    }
    if (threadIdx.x == 0) {
        const int r = c & 31, kh = r >> 4, wi = r & 15;
        const int ct = (c & ~31) + (wi >> 2) * 8 + kh * 4 + (wi & 3);
        float mean = ls[0] * invN;
        float var  = lq[0] * invN - mean * mean;
        float sc   = gamma[ct] * rsqrtf(var + EPS);
        scale[c] = sc;
        shift[c] = beta[ct] - mean * sc;
    }
}

// ------- Fused: bond finalize (blocks 0..511)  ||  atom message (512..2047) --
__global__ __launch_bounds__(256) void k_bout_amsg(
    const unsigned short* __restrict__ esyn,
    float* __restrict__ out_bond,
    const float* __restrict__ scale, const float* __restrict__ shift,
    const unsigned short* __restrict__ Ux,
    const unsigned short* __restrict__ Vx,
    const int* __restrict__ adj,
    const int* __restrict__ abadj,
    const float* __restrict__ Ub, const float* __restrict__ Vb,
    unsigned short* __restrict__ syn_a,
    float* __restrict__ psum, float* __restrict__ psq)
{
    __shared__ float ls[256][8], lq[256][8];

    if (blockIdx.x < BOUT_BLKS) {
        // -------- bond finalize: esyn(bf16,perm) -> relu(bn) f32 true cols --
        const size_t total  = (size_t)NB * (H / 8);
        const size_t stride = (size_t)BOUT_BLKS * 256;
        const int c0 = (threadIdx.x & 15) * 8;
        const f32x4 sc0 = *(const f32x4*)(scale + c0), sc1 = *(const f32x4*)(scale + c0 + 4);
        const f32x4 sh0 = *(const f32x4*)(shift + c0), sh1 = *(const f32x4*)(shift + c0 + 4);
        const int tc0 = (c0 & ~31) + (((c0 >> 2) & 3) * 8) + ((c0 >> 4) & 1) * 4;
        const int tc1 = tc0 + 8;
        for (size_t i = (size_t)blockIdx.x * 256 + threadIdx.x; i < total; i += stride) {
            u16x8 v = ((const u16x8*)esyn)[i];
            const size_t row = i >> 4;
            f32x4 o0, o1;
#pragma unroll
            for (int j = 0; j < 4; j++) {
                o0[j] = fmaxf(bf2f(v[j])     * sc0[j] + sh0[j], 0.0f);
                o1[j] = fmaxf(bf2f(v[j + 4]) * sc1[j] + sh1[j], 0.0f);
            }
            float* yp = out_bond + row * H;
            *(f32x4*)(yp + tc0) = o0;
            *(f32x4*)(yp + tc1) = o1;
        }
        return;
    }

    // -------- atom message: syn_a = (Ux+Ub) + sum_k sig(esyn[b])*(Vx[a]+Vb) --
    const int bid = blockIdx.x - BOUT_BLKS;
    const int cg = threadIdx.x & 15;
    const int rh = threadIdx.x >> 4;
    const int c0 = cg * 8;                       // permuted chunk base
    const int tc0 = (c0 & ~31) + (((c0 >> 2) & 3) * 8) + ((c0 >> 4) & 1) * 4;
    const f32x4 ub0 = *(const f32x4*)(Ub + tc0), ub1 = *(const f32x4*)(Ub + tc0 + 8);
    const f32x4 vb0 = *(const f32x4*)(Vb + tc0), vb1 = *(const f32x4*)(Vb + tc0 + 8);

    float s[8], q[8];
#pragma unroll
    for (int j = 0; j < 8; j++) { s[j] = 0.f; q[j] = 0.f; }

    const int rstride = MSG_BLKS * 16;
    int r = bid * 16 + rh;

    int2 A[3], Bv[3];
    if (r < NA) {
#pragma unroll
        for (int p = 0; p < 3; p++) {
            A[p]  = *(const int2*)(adj   + (size_t)r * 6 + 2 * p);
            Bv[p] = *(const int2*)(abadj + (size_t)r * 6 + 2 * p);
        }
    }

#pragma unroll 1
    for (; r < NA; ) {
        const int rn = r + rstride;

        const int ai[6] = {A[0].x, A[0].y, A[1].x, A[1].y, A[2].x, A[2].y};
        const int bi[6] = {Bv[0].x, Bv[0].y, Bv[1].x, Bv[1].y, Bv[2].x, Bv[2].y};

        u16x8 uv = *(const u16x8*)(Ux + (size_t)r * H + c0);

        if (rn < NA) {
#pragma unroll
            for (int p = 0; p < 3; p++) {
                A[p]  = *(const int2*)(adj   + (size_t)rn * 6 + 2 * p);
                Bv[p] = *(const int2*)(abadj + (size_t)rn * 6 + 2 * p);
            }
        }

        float v[8];
#pragma unroll
        for (int j = 0; j < 4; j++) {
            v[j]     = bf2f(uv[j])     + ub0[j];
            v[j + 4] = bf2f(uv[j + 4]) + ub1[j];
        }
#pragma unroll
        for (int k = 0; k < 6; k++) {
            u16x8 vx = *(const u16x8*)(Vx   + (size_t)ai[k] * H + c0);
            u16x8 es = *(const u16x8*)(esyn + (size_t)bi[k] * H + c0);
#pragma unroll
            for (int j = 0; j < 4; j++) {
                float g0 = 1.0f / (1.0f + __expf(-bf2f(es[j])));
                float g1 = 1.0f / (1.0f + __expf(-bf2f(es[j + 4])));
                v[j]     += g0 * (bf2f(vx[j])     + vb0[j]);
                v[j + 4] += g1 * (bf2f(vx[j + 4]) + vb1[j]);
            }
        }
        u16x8 ov;
#pragma unroll
        for (int j = 0; j < 8; j++) ov[j] = f2bf(v[j]);
        *(u16x8*)(syn_a + (size_t)r * H + c0) = ov;
#pragma unroll
        for (int j = 0; j < 8; j++) { s[j] += v[j]; q[j] += v[j] * v[j]; }

        r = rn;
    }

#pragma unroll
    for (int j = 0; j < 8; j++) { ls[threadIdx.x][j] = s[j]; lq[threadIdx.x][j] = q[j]; }
    __syncthreads();
    if (threadIdx.x < 128) {
        const int c = threadIdx.x, g = c >> 3, j = c & 7;
        float S = 0.f, Q = 0.f;
        for (int rg = 0; rg < 16; rg++) { S += ls[rg * 16 + g][j]; Q += lq[rg * 16 + g][j]; }
        psum[(size_t)bid * H + c] = S;
        psq [(size_t)bid * H + c] = Q;
    }
}

// -------- Kernel F: atom finalize: bn(syn_a)+relu + residual (Xbf bf16) ------
__global__ __launch_bounds__(256) void k_atom_out(const unsigned short* __restrict__ syn,
                                                  const unsigned short* __restrict__ xbf,
                                                  float* __restrict__ y,
                                                  const float* __restrict__ scale,
                                                  const float* __restrict__ shift)
{
    const size_t total  = (size_t)NA * (H / 8);
    const size_t stride = (size_t)gridDim.x * 256;
    const int c0 = (threadIdx.x & 15) * 8;       // permuted chunk base
    const f32x4 sc0 = *(const f32x4*)(scale + c0), sc1 = *(const f32x4*)(scale + c0 + 4);
    const f32x4 sh0 = *(const f32x4*)(shift + c0), sh1 = *(const f32x4*)(shift + c0 + 4);
    const int tc0 = (c0 & ~31) + (((c0 >> 2) & 3) * 8) + ((c0 >> 4) & 1) * 4;
    const int tc1 = tc0 + 8;
    for (size_t i = (size_t)blockIdx.x * 256 + threadIdx.x; i < total; i += stride) {
        u16x8 v = ((const u16x8*)syn)[i];
        const size_t row = i >> 4;
        const unsigned short* xp = xbf + row * H;
        u16x4 x0 = *(const u16x4*)(xp + tc0);
        u16x4 x1 = *(const u16x4*)(xp + tc1);
        f32x4 o0, o1;
#pragma unroll
        for (int j = 0; j < 4; j++) {
            o0[j] = fmaxf(bf2f(v[j])     * sc0[j] + sh0[j], 0.0f) + bf2f(x0[j]);
            o1[j] = fmaxf(bf2f(v[j + 4]) * sc1[j] + sh1[j], 0.0f) + bf2f(x1[j]);
        }
        float* yp = y + row * H;
        *(f32x4*)(yp + tc0) = o0;
        *(f32x4*)(yp + tc1) = o1;
    }
}

extern "C" void kernel_launch(void* const* d_in, const int* in_sizes, int n_in,
                              void* d_out, int out_size, void* d_ws, size_t ws_size,
                              hipStream_t stream)
{
    const float* X     = (const float*)d_in[0];
    const float* Xb    = (const float*)d_in[1];
    const int*   adj   = (const int*)d_in[2];
    const int*   abadj = (const int*)d_in[3];
    const int*   g2    = (const int*)d_in[4];
    const float* Uw = (const float*)d_in[5],  *Ub = (const float*)d_in[6];
    const float* Vw = (const float*)d_in[7],  *Vb = (const float*)d_in[8];
    const float* Aw = (const float*)d_in[9],  *Ab = (const float*)d_in[10];
    const float* Bw = (const float*)d_in[11], *Bb = (const float*)d_in[12];
    const float* Cw = (const float*)d_in[13], *Cb = (const float*)d_in[14];
    const float* gb = (const float*)d_in[15], *bb = (const float*)d_in[16];
    const float* ga = (const float*)d_in[17], *ba = (const float*)d_in[18];

    float* out_atom = (float*)d_out;
    float* out_bond = out_atom + (size_t)NA * H;

    char* ws = (char*)d_ws;
    size_t o = 0;
    unsigned short* Ux    = (unsigned short*)(ws + o); o += (size_t)NA * H * 2;
    unsigned short* Vx    = (unsigned short*)(ws + o); o += (size_t)NA * H * 2;
    unsigned short* Xbf   = (unsigned short*)(ws + o); o += (size_t)NA * H * 2;
    unsigned short* esyn  = (unsigned short*)(ws + o); o += (size_t)NB * H * 2;
    unsigned short* syn_a = (unsigned short*)(ws + o); o += (size_t)NA * H * 2;
    float* psum_b = (float*)(ws + o);  o += (size_t)EGRID * H * 4;
    float* psq_b  = (float*)(ws + o);  o += (size_t)EGRID * H * 4;
    float* psum_a = (float*)(ws + o);  o += (size_t)EGRID * H * 4;
    float* psq_a  = (float*)(ws + o);  o += (size_t)EGRID * H * 4;
    float* scale_b = (float*)(ws + o); o += 512;
    float* shift_b = (float*)(ws + o); o += 512;
    float* scale_a = (float*)(ws + o); o += 512;
    float* shift_a = (float*)(ws + o); o += 512;
    (void)o; (void)ws_size; (void)in_sizes; (void)n_in; (void)out_size;

    k_atom_gemm<<<GRID_A, 512, 0, stream>>>(X, Uw, Vw, Ux, Vx, Xbf);
    k_bond_gemm<<<GRID_B, 256, 0, stream>>>(Xb, Xbf, Aw, Bw, Cw, Ab, Bb, Cb, g2,
                                            esyn, psum_b, psq_b);
    k_bn_stats<<<H, 256, 0, stream>>>(psum_b, psq_b, GRID_B, 1.0f / NB, gb, bb, scale_b, shift_b);
    k_bout_amsg<<<FUSED_GRID, 256, 0, stream>>>(esyn, out_bond, scale_b, shift_b,
                                                Ux, Vx, adj, abadj, Ub, Vb,
                                                syn_a, psum_a, psq_a);
    k_bn_stats<<<H, 256, 0, stream>>>(psum_a, psq_a, MSG_BLKS, 1.0f / NA, ga, ba, scale_a, shift_a);
    k_atom_out<<<EGRID, 256, 0, stream>>>(syn_a, Xbf, out_atom, scale_a, shift_a);
}